// Round 10
// baseline (140.544 us; speedup 1.0000x reference)
//
#include <hip/hip_runtime.h>
#include <math.h>
#include <stdint.h>

#define HH 480
#define WW 640
#define HW (HH*WW)
#define KK 512
#define DD 256
#define KP1 513
#define NSLOT 16
#define NBX 40
#define NBY 30
#define SLOTS_PER_IMG (NBX*NBY*NSLOT)   /* 19200 */
#define SVCAP 2048
#define SBK 16                           /* sinkhorn blocks */
#define MU0 (1.0f/1024.0f)
#define MU1 (0.5f)
#define EDUST 2.71828182845904523536f    /* exp(1.0) dustbin */

// ---------------- ws layout (bytes) ----------------
#define OFF_E      16384u      /* E = exp(Z), dense 512x512 f32 */
#define OFF_SMOOTH 2473984u    /* 2 * HW f32 */
#define OFF_CAND   4931584u    /* 2 * 19200 u64 = 307200 */
#define OFF_KIDX   5238784u    /* 2 * 512 int */
#define OFF_DESC   5242880u    /* 2 * 512 * 256 f32 */
#define OFF_SBUF   6291456u    /* 2 * 512 f32 */
#define OFF_PC     6295552u    /* 2 * SBK * 513 f32 = 65664 */
#define OFF_EU     6426880u    /* 513 f32 */

// ---------------------------------------------------------------------------
// BAD pair offsets: numpy RandomState(42).randint(-8,9,(256,4)), compile-time.
// ---------------------------------------------------------------------------
struct OffsTab { int v[1024]; };
static constexpr OffsTab make_offsets() {
  OffsTab o{};
  unsigned st[624] = {};
  st[0] = 42u;
  for (int i = 1; i < 624; ++i)
    st[i] = 1812433253u*(st[i-1] ^ (st[i-1] >> 30)) + (unsigned)i;
  int idx = 624, got = 0;
  while (got < 1024) {
    if (idx == 624) {
      for (int i = 0; i < 624; ++i) {
        unsigned y = (st[i] & 0x80000000u) | (st[(i+1)%624] & 0x7fffffffu);
        st[i] = st[(i+397)%624] ^ (y >> 1) ^ ((y & 1u) ? 2567483615u : 0u);
      }
      idx = 0;
    }
    unsigned y = st[idx++];
    y ^= y >> 11;
    y ^= (y << 7)  & 2636928640u;
    y ^= (y << 15) & 4022730752u;
    y ^= y >> 18;
    unsigned mv = y & 31u;
    if (mv <= 16u) { o.v[got] = (int)mv - 8; ++got; }
  }
  return o;
}
__device__ __constant__ OffsTab OFFS = make_offsets();

// ---------------------------------------------------------------------------
// Fused detector + NMS, 32x32 output tile per 256-thread block (4 px/thread).
// Halo recompute drops from 1.9x (16x16 tiles) to 1.4x. Per-pixel arithmetic
// and slot layout byte-identical to the 16x16 version -> kpts bits unchanged.
// ---------------------------------------------------------------------------
__global__ __launch_bounds__(256) void detnms_kernel(const float* __restrict__ img0,
    const float* __restrict__ img1, float* __restrict__ smooth,
    unsigned long long* __restrict__ cand) {
  __shared__ float tile[42][42];
  __shared__ float ixA[40][40], iyA[40][40];
  __shared__ float sc[38][38];
  __shared__ float vs[32][42];
  __shared__ float vm[32][38];
  __shared__ int wsum[4], wbase[4];
  const int imgI = blockIdx.z;
  const float* img = imgI ? img1 : img0;
  const int bx0 = blockIdx.x*32, by0 = blockIdx.y*32;
  const int tx = threadIdx.x, ty = threadIdx.y, lt = ty*16+tx;
  for (int p = lt; p < 1764; p += 256) {
    int r = p/42, c = p%42;
    int gy = by0-5+r, gx = bx0-5+c;
    tile[r][c] = (gy >= 0 && gy < HH && gx >= 0 && gx < WW) ? img[gy*WW+gx] : 0.f;
  }
  __syncthreads();
  for (int p = lt; p < 1600; p += 256) {
    int r = p/40, c = p%40;
    int gy = by0-4+r, gx = bx0-4+c;
    float ix = 0.f, iy = 0.f;
    if (gy >= 0 && gy < HH && gx >= 0 && gx < WW) {
      float t00 = tile[r][c],   t01 = tile[r][c+1],   t02 = tile[r][c+2];
      float t10 = tile[r+1][c],                        t12 = tile[r+1][c+2];
      float t20 = tile[r+2][c], t21 = tile[r+2][c+1], t22 = tile[r+2][c+2];
      ix = t00*(-1.f) + t02*1.f + t10*(-2.f) + t12*2.f + t20*(-1.f) + t22*1.f;
      iy = t00*(-1.f) + t01*(-2.f) + t02*(-1.f) + t20*1.f + t21*2.f + t22*1.f;
    }
    ixA[r][c] = ix; iyA[r][c] = iy;
  }
  __syncthreads();
  const float c9 = 1.f/9.f, c25 = 1.f/25.f;
  for (int p = lt; p < 1444; p += 256) {
    int r = p/38, c = p%38;
    int gy = by0-3+r, gx = bx0-3+c;
    float v = -INFINITY;
    if (gy >= 0 && gy < HH && gx >= 0 && gx < WW) {
      float sxx = 0.f, syy = 0.f, sxy = 0.f;
      for (int dr = 0; dr < 3; ++dr)
        for (int dc = 0; dc < 3; ++dc) {
          float jx = ixA[r+dr][c+dc], jy = iyA[r+dr][c+dc];
          float pxxv = jx*jx, pyyv = jy*jy, pxyv = jx*jy;
          sxx += pxxv*c9; syy += pyyv*c9; sxy += pxyv*c9;
        }
      float tdif = sxx - syy;
      v = 0.5f * ((sxx + syy) - sqrtf(tdif*tdif + 4.f*(sxy*sxy) + 1e-12f));
    }
    sc[r][c] = v;
  }
  for (int p = lt; p < 1344; p += 256) {
    int i = p/42, c = p%42;
    vs[i][c] = tile[i+3][c] + tile[i+4][c] + tile[i+5][c] + tile[i+6][c] + tile[i+7][c];
  }
  __syncthreads();
  for (int p = lt; p < 1216; p += 256) {
    int i = p/38, c = p%38;
    float m = sc[i][c];
    m = fmaxf(m, sc[i+1][c]); m = fmaxf(m, sc[i+2][c]); m = fmaxf(m, sc[i+3][c]);
    m = fmaxf(m, sc[i+4][c]); m = fmaxf(m, sc[i+5][c]); m = fmaxf(m, sc[i+6][c]);
    vm[i][c] = m;
  }
  // 5x5 smooth for this thread's 4 pixels
  #pragma unroll
  for (int q = 0; q < 4; ++q) {
    int py = ty + 16*(q >> 1), px = tx + 16*(q & 1);
    float sm = (vs[py][px+3] + vs[py][px+4] + vs[py][px+5] + vs[py][px+6] + vs[py][px+7]) * c25;
    smooth[imgI*HW + (by0+py)*WW + (bx0+px)] = sm;
  }
  __syncthreads();
  // NMS predicates for the 4 pixels
  bool pred[4]; float cvv[4];
  #pragma unroll
  for (int q = 0; q < 4; ++q) {
    int py = ty + 16*(q >> 1), px = tx + 16*(q & 1);
    float cv = sc[py+3][px+3];
    float m = vm[py][px];
    m = fmaxf(m, vm[py][px+1]); m = fmaxf(m, vm[py][px+2]); m = fmaxf(m, vm[py][px+3]);
    m = fmaxf(m, vm[py][px+4]); m = fmaxf(m, vm[py][px+5]); m = fmaxf(m, vm[py][px+6]);
    pred[q] = (cv >= m && cv > 0.f);
    cvv[q] = cv;
  }
  const int lane = lt & 63, wid = lt >> 6;
  #pragma unroll
  for (int q = 0; q < 4; ++q) {
    unsigned long long mask = __ballot(pred[q]);
    if (lane == 0) wsum[wid] = __popcll(mask);
    __syncthreads();
    if (lt == 0) {
      int s0 = wsum[0], s1 = wsum[1], s2 = wsum[2], s3 = wsum[3];
      wbase[0] = 0; wbase[1] = s0; wbase[2] = s0+s1; wbase[3] = s0+s1+s2;
      wsum[0] = s0+s1+s2+s3;
    }
    __syncthreads();
    const int total = wsum[0];
    const int a = q >> 1, b = q & 1;
    const int subTile = (blockIdx.y*2 + a)*NBX + (blockIdx.x*2 + b);
    const size_t slotBase = (size_t)imgI*SLOTS_PER_IMG + (size_t)subTile*NSLOT;
    if (pred[q]) {
      int pos = wbase[wid] + __popcll(mask & ((1ull << lane) - 1ull));
      if (pos < NSLOT) {
        int py = ty + 16*a, px = tx + 16*b;
        int idx = (by0+py)*WW + (bx0+px);
        unsigned int ub = __float_as_uint(cvv[q]) | 0x80000000u;
        cand[slotBase + pos] = ((unsigned long long)ub << 32) | (unsigned int)(~idx);
      }
    }
    if (lt >= total && lt < NSLOT) cand[slotBase + lt] = 0ull;
    __syncthreads();
  }
}

// ---------------------------------------------------------------------------
// Fused top-512 select (unchanged since round 7).
// ---------------------------------------------------------------------------
__global__ __launch_bounds__(1024) void select2_kernel(const unsigned long long* __restrict__ cand,
    float* __restrict__ kptsOut, int* __restrict__ kidx) {
  __shared__ unsigned long long sk[SVCAP];
  __shared__ int hist[1024];
  __shared__ int sB1, sB2, sNeed, sCount;
  const int imgI = blockIdx.x, t = threadIdx.x;
  const unsigned long long* cd = cand + (size_t)imgI*SLOTS_PER_IMG;
  unsigned long long kreg[19];
  #pragma unroll
  for (int r = 0; r < 19; ++r) {
    int i = t + r*1024;
    kreg[r] = (i < SLOTS_PER_IMG) ? cd[i] : 0ull;
  }
  hist[t] = 0;
  if (t == 0) { sB1 = -1; sB2 = 0; sCount = 0; }
  __syncthreads();
  #pragma unroll
  for (int r = 0; r < 19; ++r)
    if (kreg[r]) atomicAdd(&hist[(int)(kreg[r] >> 54)], 1);
  __syncthreads();
  for (int d = 1; d < 1024; d <<= 1) {
    int vv = hist[t] + ((t + d < 1024) ? hist[t + d] : 0);
    __syncthreads();
    hist[t] = vv;
    __syncthreads();
  }
  if (hist[t] >= KK) atomicMax(&sB1, t);
  __syncthreads();
  const int b1 = sB1;
  if (t == 0 && b1 >= 0) sNeed = KK - ((b1 < 1023) ? hist[b1 + 1] : 0);
  __syncthreads();
  int b2 = 0;
  if (b1 >= 0) {
    hist[t] = 0;
    __syncthreads();
    #pragma unroll
    for (int r = 0; r < 19; ++r) {
      unsigned long long k = kreg[r];
      if (k && (int)(k >> 54) == b1) atomicAdd(&hist[(int)(k >> 44) & 1023], 1);
    }
    __syncthreads();
    for (int d = 1; d < 1024; d <<= 1) {
      int vv = hist[t] + ((t + d < 1024) ? hist[t + d] : 0);
      __syncthreads();
      hist[t] = vv;
      __syncthreads();
    }
    if (hist[t] >= sNeed) atomicMax(&sB2, t);
    __syncthreads();
    b2 = sB2;
  }
  #pragma unroll
  for (int r = 0; r < 19; ++r) {
    unsigned long long k = kreg[r];
    if (k) {
      int bin1 = (int)(k >> 54);
      if (bin1 > b1 || (bin1 == b1 && ((int)(k >> 44) & 1023) >= b2)) {
        int pos = atomicAdd(&sCount, 1);
        if (pos < SVCAP) sk[pos] = k;
      }
    }
  }
  __syncthreads();
  const int n = (sCount < SVCAP) ? sCount : SVCAP;
  for (int k = n + t; k < KK; k += 1024) {
    kptsOut[imgI*2*KK + 2*k]     = -1.f;
    kptsOut[imgI*2*KK + 2*k + 1] = -1.f;
    kidx[imgI*KK + k] = -1;
  }
  for (int i = t; i < n; i += 1024) {
    unsigned long long key = sk[i];
    int r = 0;
    for (int m = 0; m < n; ++m) r += (sk[m] > key) ? 1 : 0;
    if (r < KK) {
      int id = (int)(~(unsigned int)(key & 0xFFFFFFFFull));
      kptsOut[imgI*2*KK + 2*r]     = (float)(id / WW);
      kptsOut[imgI*2*KK + 2*r + 1] = (float)(id % WW);
      kidx[imgI*KK + r] = id;
    }
  }
}

// ---------------------------------------------------------------------------
// Per-keypoint BAD descriptor + L2 norm + squared-norm (unchanged).
// ---------------------------------------------------------------------------
__global__ __launch_bounds__(256) void desc_kernel(const float* __restrict__ smooth,
    const int* __restrict__ kidx, float* __restrict__ desc, float* __restrict__ sbuf) {
  __shared__ float wsum[4];
  const int k = blockIdx.x, imgI = blockIdx.y;
  const int j = threadIdx.x;
  const int id = kidx[imgI*KK + k];
  float val = 0.f;
  if (id >= 0) {
    int y = id / WW, x = id % WW;
    int o0 = OFFS.v[4*j], o1 = OFFS.v[4*j+1], o2 = OFFS.v[4*j+2], o3 = OFFS.v[4*j+3];
    const float* sm = smooth + imgI*HW;
    int ya = min(max(y+o0, 0), HH-1), xa = min(max(x+o1, 0), WW-1);
    int yb = min(max(y+o2, 0), HH-1), xb = min(max(x+o3, 0), WW-1);
    val = sm[ya*WW + xa] - sm[yb*WW + xb];
  }
  float ss = val*val;
  for (int off = 32; off; off >>= 1) ss += __shfl_down(ss, off);
  if ((j & 63) == 0) wsum[j >> 6] = ss;
  __syncthreads();
  if (j == 0) wsum[0] = wsum[0] + wsum[1] + wsum[2] + wsum[3];
  __syncthreads();
  float tot = wsum[0];
  float inv = 1.f / (sqrtf(tot) + 1e-12f);
  desc[((size_t)imgI*KK + k)*DD + j] = val * inv;
  if (j == 0) sbuf[imgI*KK + k] = tot * inv * inv;
}

// ---------------------------------------------------------------------------
// E = exp(-sqrt(clip(s1+s2-2*d1.d2, 1e-12)))  (dense 512x512; dustbins are
// the constant EDUST, never stored). 32x32 tile, 2x2 outputs per thread.
// ---------------------------------------------------------------------------
__global__ __launch_bounds__(256) void zbuild_kernel(const float* __restrict__ desc,
    const float* __restrict__ sbuf, float* __restrict__ E) {
  __shared__ float sA[32][260], sB[32][260];
  const int ty = threadIdx.y, tx = threadIdx.x;
  const int i0 = blockIdx.y*32, j0 = blockIdx.x*32;
  const int lt = ty*16 + tx;
  for (int p = lt; p < 32*DD; p += 256) {
    int r = p >> 8, c = p & 255;
    sA[r][c] = desc[((size_t)(i0 + r))*DD + c];
    sB[r][c] = desc[((size_t)(KK + j0 + r))*DD + c];
  }
  __syncthreads();
  const float4* pa0 = (const float4*)&sA[ty][0];
  const float4* pa1 = (const float4*)&sA[ty+16][0];
  const float4* pb0 = (const float4*)&sB[tx][0];
  const float4* pb1 = (const float4*)&sB[tx+16][0];
  float a00 = 0.f, a01 = 0.f, a10 = 0.f, a11 = 0.f;
  for (int c4 = 0; c4 < DD/4; ++c4) {
    float4 a0 = pa0[c4], a1 = pa1[c4], b0 = pb0[c4], b1 = pb1[c4];
    a00 += a0.x*b0.x; a00 += a0.y*b0.y; a00 += a0.z*b0.z; a00 += a0.w*b0.w;
    a01 += a0.x*b1.x; a01 += a0.y*b1.y; a01 += a0.z*b1.z; a01 += a0.w*b1.w;
    a10 += a1.x*b0.x; a10 += a1.y*b0.y; a10 += a1.z*b0.z; a10 += a1.w*b0.w;
    a11 += a1.x*b1.x; a11 += a1.y*b1.y; a11 += a1.z*b1.z; a11 += a1.w*b1.w;
  }
  const float s0 = sbuf[i0 + ty], s0b = sbuf[i0 + ty + 16];
  const float s1 = sbuf[KK + j0 + tx], s1b = sbuf[KK + j0 + tx + 16];
  E[(size_t)(i0+ty)   *KK + j0+tx]    = expf(-sqrtf(fmaxf(s0  + s1  - 2.f*a00, 1e-12f)));
  E[(size_t)(i0+ty)   *KK + j0+tx+16] = expf(-sqrtf(fmaxf(s0  + s1b - 2.f*a01, 1e-12f)));
  E[(size_t)(i0+ty+16)*KK + j0+tx]    = expf(-sqrtf(fmaxf(s0b + s1  - 2.f*a10, 1e-12f)));
  E[(size_t)(i0+ty+16)*KK + j0+tx+16] = expf(-sqrtf(fmaxf(s0b + s1b - 2.f*a11, 1e-12f)));
}

// ---------------------------------------------------------------------------
// Transcendental-free Sinkhorn step on E = exp(Z), 16 blocks x 16 waves,
// 2 rows per wave (wave 255 also owns the dust row).
//   ev_j = nu_j / G_j (mode 0: ev=1);  S_i = sum_j E_ij*ev_j + EDUST*ev_512
//   eu_i = mu_i / S_i;  slice G_j(block) = sum_{rows in block} E_ij*eu_i
//   mode 2: probs = E*eu*ev*1024.   All sums fixed-order -> deterministic.
// ---------------------------------------------------------------------------
__global__ __launch_bounds__(1024) void sink_step_kernel(const float* __restrict__ E,
    const float* __restrict__ PcolIn, float* __restrict__ PcolOut,
    float* __restrict__ euBuf, float* __restrict__ probs, int mode) {
  __shared__ float ev[KP1];
  __shared__ float pcolw[16][520];
  const int t = threadIdx.x, b = blockIdx.x;
  const int widx = t >> 6, lane = t & 63;
  const int gw = b*16 + widx;          // wave 0..255; rows 2*gw, 2*gw+1
  const int j0 = lane*8;
  const int r0 = 2*gw, r1 = 2*gw + 1;
  const bool hasDust = (gw == 255);
  if (mode == 0) {
    for (int j = t; j < KP1; j += 1024) ev[j] = 1.f;
  } else {
    for (int j = t; j < KP1; j += 1024) {
      float s = 0.f;
      #pragma unroll
      for (int w = 0; w < SBK; ++w) s += PcolIn[w*KP1 + j];
      float nu = (j < KK) ? MU0 : MU1;
      ev[j] = nu / s;
    }
  }
  __syncthreads();
  float4 va = *(const float4*)&ev[j0];
  float4 vb = *(const float4*)&ev[j0+4];
  float evv[8] = {va.x,va.y,va.z,va.w,vb.x,vb.y,vb.z,vb.w};
  const float ev512 = ev[512];
  const float* er0 = E + (size_t)r0*KK;
  const float* er1 = E + (size_t)r1*KK;
  float4 e00 = *(const float4*)&er0[j0];
  float4 e01 = *(const float4*)&er0[j0+4];
  float4 e10 = *(const float4*)&er1[j0];
  float4 e11 = *(const float4*)&er1[j0+4];
  float ee0[8] = {e00.x,e00.y,e00.z,e00.w,e01.x,e01.y,e01.z,e01.w};
  float ee1[8] = {e10.x,e10.y,e10.z,e10.w,e11.x,e11.y,e11.z,e11.w};
  if (mode == 2) {
    const float eu0 = euBuf[r0], eu1 = euBuf[r1];
    float* pr0 = probs + (size_t)r0*KP1;
    float* pr1 = probs + (size_t)r1*KP1;
    #pragma unroll
    for (int q = 0; q < 8; ++q) {
      pr0[j0+q] = ee0[q] * eu0 * evv[q] * 1024.f;
      pr1[j0+q] = ee1[q] * eu1 * evv[q] * 1024.f;
    }
    if (lane == 0) {
      pr0[512] = EDUST * eu0 * ev512 * 1024.f;
      pr1[512] = EDUST * eu1 * ev512 * 1024.f;
    }
    if (hasDust) {
      const float euD = euBuf[512];
      float* pd = probs + (size_t)512*KP1;
      #pragma unroll
      for (int q = 0; q < 8; ++q) pd[j0+q] = EDUST * euD * evv[q] * 1024.f;
      if (lane == 0) pd[512] = EDUST * euD * ev512 * 1024.f;
    }
    return;
  }
  // ---- row pass (pure FMA) ----
  float S0 = 0.f, S1 = 0.f;
  #pragma unroll
  for (int q = 0; q < 8; ++q) { S0 += ee0[q] * evv[q]; S1 += ee1[q] * evv[q]; }
  if (lane == 0) { S0 += EDUST * ev512; S1 += EDUST * ev512; }
  #pragma unroll
  for (int off = 32; off; off >>= 1) {
    S0 += __shfl_xor(S0, off);
    S1 += __shfl_xor(S1, off);
  }
  const float eu0 = MU0 / S0, eu1 = MU0 / S1;
  if (lane == 0) { euBuf[r0] = eu0; euBuf[r1] = eu1; }
  float pacc[8];
  #pragma unroll
  for (int q = 0; q < 8; ++q) pacc[q] = ee0[q] * eu0 + ee1[q] * eu1;
  float pacc8 = EDUST * eu0 + EDUST * eu1;
  if (hasDust) {          // dust row: S_d = EDUST * sum(ev)
    float Sd = 0.f;
    #pragma unroll
    for (int q = 0; q < 8; ++q) Sd += evv[q];
    if (lane == 0) Sd += ev512;
    #pragma unroll
    for (int off = 32; off; off >>= 1) Sd += __shfl_xor(Sd, off);
    Sd *= EDUST;
    const float euD = MU1 / Sd;
    if (lane == 0) euBuf[512] = euD;
    #pragma unroll
    for (int q = 0; q < 8; ++q) pacc[q] += EDUST * euD;
    pacc8 += EDUST * euD;
  }
  *(float4*)&pcolw[widx][j0]   = make_float4(pacc[0], pacc[1], pacc[2], pacc[3]);
  *(float4*)&pcolw[widx][j0+4] = make_float4(pacc[4], pacc[5], pacc[6], pacc[7]);
  if (lane == 0) pcolw[widx][512] = pacc8;
  __syncthreads();
  float* pc = PcolOut + b*KP1;
  for (int j = t; j < KP1; j += 1024) {
    float s = 0.f;
    #pragma unroll
    for (int w = 0; w < 16; ++w) s += pcolw[w][j];
    pc[j] = s;
  }
}

extern "C" void kernel_launch(void* const* d_in, const int* in_sizes, int n_in,
                              void* d_out, int out_size, void* d_ws, size_t ws_size,
                              hipStream_t stream) {
  const float* img1 = (const float*)d_in[0];
  const float* img2 = (const float*)d_in[1];
  float* out = (float*)d_out;
  char* ws = (char*)d_ws;

  float* smooth = (float*)(ws + OFF_SMOOTH);
  unsigned long long* cand = (unsigned long long*)(ws + OFF_CAND);
  int*   kidx   = (int*)  (ws + OFF_KIDX);
  float* desc   = (float*)(ws + OFF_DESC);
  float* sbuf   = (float*)(ws + OFF_SBUF);
  float* E      = (float*)(ws + OFF_E);
  float* pcA    = (float*)(ws + OFF_PC);
  float* pcB    = (float*)(ws + OFF_PC) + SBK*KP1;
  float* euBuf  = (float*)(ws + OFF_EU);
  float* probsOut = out + 2*KK*2;

  detnms_kernel<<<dim3(20, 15, 2), dim3(16, 16), 0, stream>>>(img1, img2, smooth, cand);
  select2_kernel<<<2, 1024, 0, stream>>>(cand, out, kidx);
  desc_kernel<<<dim3(KK, 2), 256, 0, stream>>>(smooth, kidx, desc, sbuf);
  zbuild_kernel<<<dim3(16, 16), dim3(16, 16), 0, stream>>>(desc, sbuf, E);

  // L0: ev=1, row pass -> pcA
  sink_step_kernel<<<SBK, 1024, 0, stream>>>(E, pcB, pcA, euBuf, probsOut, 0);
  int ping = 0;  // latest slices in pcA
  for (int it = 1; it < 20; ++it) {
    float* pin  = ping ? pcB : pcA;
    float* pout = ping ? pcA : pcB;
    sink_step_kernel<<<SBK, 1024, 0, stream>>>(E, pin, pout, euBuf, probsOut, 1);
    ping ^= 1;
  }
  {
    float* pin = ping ? pcB : pcA;
    sink_step_kernel<<<SBK, 1024, 0, stream>>>(E, pin, pcA, euBuf, probsOut, 2);
  }
}

// Round 11
// 139.604 us; speedup vs baseline: 1.0067x; 1.0067x over previous
//
#include <hip/hip_runtime.h>
#include <math.h>
#include <stdint.h>

#define HH 480
#define WW 640
#define HW (HH*WW)
#define KK 512
#define DD 256
#define KP1 513
#define NSLOT 16
#define NBX 40
#define NBY 30
#define SLOTS_PER_IMG (NBX*NBY*NSLOT)   /* 19200 */
#define SVCAP 2048
#define SBK 16                           /* sinkhorn blocks */
#define MU0 (1.0f/1024.0f)
#define MU1 (0.5f)
#define EDUST 2.71828182845904523536f    /* exp(1.0) dustbin */

// ---------------- ws layout (bytes) ----------------
#define OFF_E      16384u      /* E = exp(Z), dense 512x512 f32 */
#define OFF_SMOOTH 2473984u    /* 2 * HW f32 */
#define OFF_CAND   4931584u    /* 2 * 19200 u64 = 307200 */
#define OFF_KIDX   5238784u    /* 2 * 512 int */
#define OFF_DESC   5242880u    /* 2 * 512 * 256 f32 */
#define OFF_SBUF   6291456u    /* 2 * 512 f32 */
#define OFF_PC     6295552u    /* 2 * SBK * 513 f32 = 65664 */
#define OFF_EU     6426880u    /* 513 f32 */

// ---------------------------------------------------------------------------
// BAD pair offsets: numpy RandomState(42).randint(-8,9,(256,4)), compile-time.
// ---------------------------------------------------------------------------
struct OffsTab { int v[1024]; };
static constexpr OffsTab make_offsets() {
  OffsTab o{};
  unsigned st[624] = {};
  st[0] = 42u;
  for (int i = 1; i < 624; ++i)
    st[i] = 1812433253u*(st[i-1] ^ (st[i-1] >> 30)) + (unsigned)i;
  int idx = 624, got = 0;
  while (got < 1024) {
    if (idx == 624) {
      for (int i = 0; i < 624; ++i) {
        unsigned y = (st[i] & 0x80000000u) | (st[(i+1)%624] & 0x7fffffffu);
        st[i] = st[(i+397)%624] ^ (y >> 1) ^ ((y & 1u) ? 2567483615u : 0u);
      }
      idx = 0;
    }
    unsigned y = st[idx++];
    y ^= y >> 11;
    y ^= (y << 7)  & 2636928640u;
    y ^= (y << 15) & 4022730752u;
    y ^= y >> 18;
    unsigned mv = y & 31u;
    if (mv <= 16u) { o.v[got] = (int)mv - 8; ++got; }
  }
  return o;
}
__device__ __constant__ OffsTab OFFS = make_offsets();

// ---------------------------------------------------------------------------
// Fused detector + NMS, 32x32 output tile per 256-thread block (4 px/thread).
// Halo recompute drops from 1.9x (16x16 tiles) to 1.4x. Per-pixel arithmetic
// and slot layout byte-identical to the 16x16 version -> kpts bits unchanged.
// ---------------------------------------------------------------------------
__global__ __launch_bounds__(256) void detnms_kernel(const float* __restrict__ img0,
    const float* __restrict__ img1, float* __restrict__ smooth,
    unsigned long long* __restrict__ cand) {
  __shared__ float tile[42][42];
  __shared__ float ixA[40][40], iyA[40][40];
  __shared__ float sc[38][38];
  __shared__ float vs[32][42];
  __shared__ float vm[32][38];
  __shared__ int wsum[4], wbase[4];
  const int imgI = blockIdx.z;
  const float* img = imgI ? img1 : img0;
  const int bx0 = blockIdx.x*32, by0 = blockIdx.y*32;
  const int tx = threadIdx.x, ty = threadIdx.y, lt = ty*16+tx;
  for (int p = lt; p < 1764; p += 256) {
    int r = p/42, c = p%42;
    int gy = by0-5+r, gx = bx0-5+c;
    tile[r][c] = (gy >= 0 && gy < HH && gx >= 0 && gx < WW) ? img[gy*WW+gx] : 0.f;
  }
  __syncthreads();
  for (int p = lt; p < 1600; p += 256) {
    int r = p/40, c = p%40;
    int gy = by0-4+r, gx = bx0-4+c;
    float ix = 0.f, iy = 0.f;
    if (gy >= 0 && gy < HH && gx >= 0 && gx < WW) {
      float t00 = tile[r][c],   t01 = tile[r][c+1],   t02 = tile[r][c+2];
      float t10 = tile[r+1][c],                        t12 = tile[r+1][c+2];
      float t20 = tile[r+2][c], t21 = tile[r+2][c+1], t22 = tile[r+2][c+2];
      ix = t00*(-1.f) + t02*1.f + t10*(-2.f) + t12*2.f + t20*(-1.f) + t22*1.f;
      iy = t00*(-1.f) + t01*(-2.f) + t02*(-1.f) + t20*1.f + t21*2.f + t22*1.f;
    }
    ixA[r][c] = ix; iyA[r][c] = iy;
  }
  __syncthreads();
  const float c9 = 1.f/9.f, c25 = 1.f/25.f;
  for (int p = lt; p < 1444; p += 256) {
    int r = p/38, c = p%38;
    int gy = by0-3+r, gx = bx0-3+c;
    float v = -INFINITY;
    if (gy >= 0 && gy < HH && gx >= 0 && gx < WW) {
      float sxx = 0.f, syy = 0.f, sxy = 0.f;
      for (int dr = 0; dr < 3; ++dr)
        for (int dc = 0; dc < 3; ++dc) {
          float jx = ixA[r+dr][c+dc], jy = iyA[r+dr][c+dc];
          float pxxv = jx*jx, pyyv = jy*jy, pxyv = jx*jy;
          sxx += pxxv*c9; syy += pyyv*c9; sxy += pxyv*c9;
        }
      float tdif = sxx - syy;
      v = 0.5f * ((sxx + syy) - sqrtf(tdif*tdif + 4.f*(sxy*sxy) + 1e-12f));
    }
    sc[r][c] = v;
  }
  for (int p = lt; p < 1344; p += 256) {
    int i = p/42, c = p%42;
    vs[i][c] = tile[i+3][c] + tile[i+4][c] + tile[i+5][c] + tile[i+6][c] + tile[i+7][c];
  }
  __syncthreads();
  for (int p = lt; p < 1216; p += 256) {
    int i = p/38, c = p%38;
    float m = sc[i][c];
    m = fmaxf(m, sc[i+1][c]); m = fmaxf(m, sc[i+2][c]); m = fmaxf(m, sc[i+3][c]);
    m = fmaxf(m, sc[i+4][c]); m = fmaxf(m, sc[i+5][c]); m = fmaxf(m, sc[i+6][c]);
    vm[i][c] = m;
  }
  // 5x5 smooth for this thread's 4 pixels
  #pragma unroll
  for (int q = 0; q < 4; ++q) {
    int py = ty + 16*(q >> 1), px = tx + 16*(q & 1);
    float sm = (vs[py][px+3] + vs[py][px+4] + vs[py][px+5] + vs[py][px+6] + vs[py][px+7]) * c25;
    smooth[imgI*HW + (by0+py)*WW + (bx0+px)] = sm;
  }
  __syncthreads();
  // NMS predicates for the 4 pixels
  bool pred[4]; float cvv[4];
  #pragma unroll
  for (int q = 0; q < 4; ++q) {
    int py = ty + 16*(q >> 1), px = tx + 16*(q & 1);
    float cv = sc[py+3][px+3];
    float m = vm[py][px];
    m = fmaxf(m, vm[py][px+1]); m = fmaxf(m, vm[py][px+2]); m = fmaxf(m, vm[py][px+3]);
    m = fmaxf(m, vm[py][px+4]); m = fmaxf(m, vm[py][px+5]); m = fmaxf(m, vm[py][px+6]);
    pred[q] = (cv >= m && cv > 0.f);
    cvv[q] = cv;
  }
  const int lane = lt & 63, wid = lt >> 6;
  #pragma unroll
  for (int q = 0; q < 4; ++q) {
    unsigned long long mask = __ballot(pred[q]);
    if (lane == 0) wsum[wid] = __popcll(mask);
    __syncthreads();
    if (lt == 0) {
      int s0 = wsum[0], s1 = wsum[1], s2 = wsum[2], s3 = wsum[3];
      wbase[0] = 0; wbase[1] = s0; wbase[2] = s0+s1; wbase[3] = s0+s1+s2;
      wsum[0] = s0+s1+s2+s3;
    }
    __syncthreads();
    const int total = wsum[0];
    const int a = q >> 1, b = q & 1;
    const int subTile = (blockIdx.y*2 + a)*NBX + (blockIdx.x*2 + b);
    const size_t slotBase = (size_t)imgI*SLOTS_PER_IMG + (size_t)subTile*NSLOT;
    if (pred[q]) {
      int pos = wbase[wid] + __popcll(mask & ((1ull << lane) - 1ull));
      if (pos < NSLOT) {
        int py = ty + 16*a, px = tx + 16*b;
        int idx = (by0+py)*WW + (bx0+px);
        unsigned int ub = __float_as_uint(cvv[q]) | 0x80000000u;
        cand[slotBase + pos] = ((unsigned long long)ub << 32) | (unsigned int)(~idx);
      }
    }
    if (lt >= total && lt < NSLOT) cand[slotBase + lt] = 0ull;
    __syncthreads();
  }
}

// ---------------------------------------------------------------------------
// Fused top-512 select (unchanged since round 7).
// ---------------------------------------------------------------------------
__global__ __launch_bounds__(1024) void select2_kernel(const unsigned long long* __restrict__ cand,
    float* __restrict__ kptsOut, int* __restrict__ kidx) {
  __shared__ unsigned long long sk[SVCAP];
  __shared__ int hist[1024];
  __shared__ int sB1, sB2, sNeed, sCount;
  const int imgI = blockIdx.x, t = threadIdx.x;
  const unsigned long long* cd = cand + (size_t)imgI*SLOTS_PER_IMG;
  unsigned long long kreg[19];
  #pragma unroll
  for (int r = 0; r < 19; ++r) {
    int i = t + r*1024;
    kreg[r] = (i < SLOTS_PER_IMG) ? cd[i] : 0ull;
  }
  hist[t] = 0;
  if (t == 0) { sB1 = -1; sB2 = 0; sCount = 0; }
  __syncthreads();
  #pragma unroll
  for (int r = 0; r < 19; ++r)
    if (kreg[r]) atomicAdd(&hist[(int)(kreg[r] >> 54)], 1);
  __syncthreads();
  for (int d = 1; d < 1024; d <<= 1) {
    int vv = hist[t] + ((t + d < 1024) ? hist[t + d] : 0);
    __syncthreads();
    hist[t] = vv;
    __syncthreads();
  }
  if (hist[t] >= KK) atomicMax(&sB1, t);
  __syncthreads();
  const int b1 = sB1;
  if (t == 0 && b1 >= 0) sNeed = KK - ((b1 < 1023) ? hist[b1 + 1] : 0);
  __syncthreads();
  int b2 = 0;
  if (b1 >= 0) {
    hist[t] = 0;
    __syncthreads();
    #pragma unroll
    for (int r = 0; r < 19; ++r) {
      unsigned long long k = kreg[r];
      if (k && (int)(k >> 54) == b1) atomicAdd(&hist[(int)(k >> 44) & 1023], 1);
    }
    __syncthreads();
    for (int d = 1; d < 1024; d <<= 1) {
      int vv = hist[t] + ((t + d < 1024) ? hist[t + d] : 0);
      __syncthreads();
      hist[t] = vv;
      __syncthreads();
    }
    if (hist[t] >= sNeed) atomicMax(&sB2, t);
    __syncthreads();
    b2 = sB2;
  }
  #pragma unroll
  for (int r = 0; r < 19; ++r) {
    unsigned long long k = kreg[r];
    if (k) {
      int bin1 = (int)(k >> 54);
      if (bin1 > b1 || (bin1 == b1 && ((int)(k >> 44) & 1023) >= b2)) {
        int pos = atomicAdd(&sCount, 1);
        if (pos < SVCAP) sk[pos] = k;
      }
    }
  }
  __syncthreads();
  const int n = (sCount < SVCAP) ? sCount : SVCAP;
  for (int k = n + t; k < KK; k += 1024) {
    kptsOut[imgI*2*KK + 2*k]     = -1.f;
    kptsOut[imgI*2*KK + 2*k + 1] = -1.f;
    kidx[imgI*KK + k] = -1;
  }
  for (int i = t; i < n; i += 1024) {
    unsigned long long key = sk[i];
    int r = 0;
    for (int m = 0; m < n; ++m) r += (sk[m] > key) ? 1 : 0;
    if (r < KK) {
      int id = (int)(~(unsigned int)(key & 0xFFFFFFFFull));
      kptsOut[imgI*2*KK + 2*r]     = (float)(id / WW);
      kptsOut[imgI*2*KK + 2*r + 1] = (float)(id % WW);
      kidx[imgI*KK + r] = id;
    }
  }
}

// ---------------------------------------------------------------------------
// Per-keypoint BAD descriptor + L2 norm + squared-norm (unchanged).
// ---------------------------------------------------------------------------
__global__ __launch_bounds__(256) void desc_kernel(const float* __restrict__ smooth,
    const int* __restrict__ kidx, float* __restrict__ desc, float* __restrict__ sbuf) {
  __shared__ float wsum[4];
  const int k = blockIdx.x, imgI = blockIdx.y;
  const int j = threadIdx.x;
  const int id = kidx[imgI*KK + k];
  float val = 0.f;
  if (id >= 0) {
    int y = id / WW, x = id % WW;
    int o0 = OFFS.v[4*j], o1 = OFFS.v[4*j+1], o2 = OFFS.v[4*j+2], o3 = OFFS.v[4*j+3];
    const float* sm = smooth + imgI*HW;
    int ya = min(max(y+o0, 0), HH-1), xa = min(max(x+o1, 0), WW-1);
    int yb = min(max(y+o2, 0), HH-1), xb = min(max(x+o3, 0), WW-1);
    val = sm[ya*WW + xa] - sm[yb*WW + xb];
  }
  float ss = val*val;
  for (int off = 32; off; off >>= 1) ss += __shfl_down(ss, off);
  if ((j & 63) == 0) wsum[j >> 6] = ss;
  __syncthreads();
  if (j == 0) wsum[0] = wsum[0] + wsum[1] + wsum[2] + wsum[3];
  __syncthreads();
  float tot = wsum[0];
  float inv = 1.f / (sqrtf(tot) + 1e-12f);
  desc[((size_t)imgI*KK + k)*DD + j] = val * inv;
  if (j == 0) sbuf[imgI*KK + k] = tot * inv * inv;
}

// ---------------------------------------------------------------------------
// E = exp(-sqrt(clip(s1+s2-2*d1.d2, 1e-12)))  (dense 512x512; dustbins are
// the constant EDUST, never stored). 32x32 tile, 2x2 outputs per thread.
// ---------------------------------------------------------------------------
__global__ __launch_bounds__(256) void zbuild_kernel(const float* __restrict__ desc,
    const float* __restrict__ sbuf, float* __restrict__ E) {
  __shared__ float sA[32][260], sB[32][260];
  const int ty = threadIdx.y, tx = threadIdx.x;
  const int i0 = blockIdx.y*32, j0 = blockIdx.x*32;
  const int lt = ty*16 + tx;
  for (int p = lt; p < 32*DD; p += 256) {
    int r = p >> 8, c = p & 255;
    sA[r][c] = desc[((size_t)(i0 + r))*DD + c];
    sB[r][c] = desc[((size_t)(KK + j0 + r))*DD + c];
  }
  __syncthreads();
  const float4* pa0 = (const float4*)&sA[ty][0];
  const float4* pa1 = (const float4*)&sA[ty+16][0];
  const float4* pb0 = (const float4*)&sB[tx][0];
  const float4* pb1 = (const float4*)&sB[tx+16][0];
  float a00 = 0.f, a01 = 0.f, a10 = 0.f, a11 = 0.f;
  for (int c4 = 0; c4 < DD/4; ++c4) {
    float4 a0 = pa0[c4], a1 = pa1[c4], b0 = pb0[c4], b1 = pb1[c4];
    a00 += a0.x*b0.x; a00 += a0.y*b0.y; a00 += a0.z*b0.z; a00 += a0.w*b0.w;
    a01 += a0.x*b1.x; a01 += a0.y*b1.y; a01 += a0.z*b1.z; a01 += a0.w*b1.w;
    a10 += a1.x*b0.x; a10 += a1.y*b0.y; a10 += a1.z*b0.z; a10 += a1.w*b0.w;
    a11 += a1.x*b1.x; a11 += a1.y*b1.y; a11 += a1.z*b1.z; a11 += a1.w*b1.w;
  }
  const float s0 = sbuf[i0 + ty], s0b = sbuf[i0 + ty + 16];
  const float s1 = sbuf[KK + j0 + tx], s1b = sbuf[KK + j0 + tx + 16];
  E[(size_t)(i0+ty)   *KK + j0+tx]    = expf(-sqrtf(fmaxf(s0  + s1  - 2.f*a00, 1e-12f)));
  E[(size_t)(i0+ty)   *KK + j0+tx+16] = expf(-sqrtf(fmaxf(s0  + s1b - 2.f*a01, 1e-12f)));
  E[(size_t)(i0+ty+16)*KK + j0+tx]    = expf(-sqrtf(fmaxf(s0b + s1  - 2.f*a10, 1e-12f)));
  E[(size_t)(i0+ty+16)*KK + j0+tx+16] = expf(-sqrtf(fmaxf(s0b + s1b - 2.f*a11, 1e-12f)));
}

// ---------------------------------------------------------------------------
// Transcendental-free Sinkhorn step on E = exp(Z), 16 blocks x 16 waves,
// 2 rows per wave (wave 255 also owns the dust row).
//   ev_j = nu_j / G_j (mode 0: ev=1);  S_i = sum_j E_ij*ev_j + EDUST*ev_512
//   eu_i = mu_i / S_i;  slice G_j(block) = sum_{rows in block} E_ij*eu_i
//   mode 2: probs = E*eu*ev*1024.   All sums fixed-order -> deterministic.
// ---------------------------------------------------------------------------
__global__ __launch_bounds__(1024) void sink_step_kernel(const float* __restrict__ E,
    const float* __restrict__ PcolIn, float* __restrict__ PcolOut,
    float* __restrict__ euBuf, float* __restrict__ probs, int mode) {
  __shared__ float ev[KP1];
  __shared__ float pcolw[16][520];
  const int t = threadIdx.x, b = blockIdx.x;
  const int widx = t >> 6, lane = t & 63;
  const int gw = b*16 + widx;          // wave 0..255; rows 2*gw, 2*gw+1
  const int j0 = lane*8;
  const int r0 = 2*gw, r1 = 2*gw + 1;
  const bool hasDust = (gw == 255);
  if (mode == 0) {
    for (int j = t; j < KP1; j += 1024) ev[j] = 1.f;
  } else {
    for (int j = t; j < KP1; j += 1024) {
      float s = 0.f;
      #pragma unroll
      for (int w = 0; w < SBK; ++w) s += PcolIn[w*KP1 + j];
      float nu = (j < KK) ? MU0 : MU1;
      ev[j] = nu / s;
    }
  }
  __syncthreads();
  float4 va = *(const float4*)&ev[j0];
  float4 vb = *(const float4*)&ev[j0+4];
  float evv[8] = {va.x,va.y,va.z,va.w,vb.x,vb.y,vb.z,vb.w};
  const float ev512 = ev[512];
  const float* er0 = E + (size_t)r0*KK;
  const float* er1 = E + (size_t)r1*KK;
  float4 e00 = *(const float4*)&er0[j0];
  float4 e01 = *(const float4*)&er0[j0+4];
  float4 e10 = *(const float4*)&er1[j0];
  float4 e11 = *(const float4*)&er1[j0+4];
  float ee0[8] = {e00.x,e00.y,e00.z,e00.w,e01.x,e01.y,e01.z,e01.w};
  float ee1[8] = {e10.x,e10.y,e10.z,e10.w,e11.x,e11.y,e11.z,e11.w};
  if (mode == 2) {
    const float eu0 = euBuf[r0], eu1 = euBuf[r1];
    float* pr0 = probs + (size_t)r0*KP1;
    float* pr1 = probs + (size_t)r1*KP1;
    #pragma unroll
    for (int q = 0; q < 8; ++q) {
      pr0[j0+q] = ee0[q] * eu0 * evv[q] * 1024.f;
      pr1[j0+q] = ee1[q] * eu1 * evv[q] * 1024.f;
    }
    if (lane == 0) {
      pr0[512] = EDUST * eu0 * ev512 * 1024.f;
      pr1[512] = EDUST * eu1 * ev512 * 1024.f;
    }
    if (hasDust) {
      const float euD = euBuf[512];
      float* pd = probs + (size_t)512*KP1;
      #pragma unroll
      for (int q = 0; q < 8; ++q) pd[j0+q] = EDUST * euD * evv[q] * 1024.f;
      if (lane == 0) pd[512] = EDUST * euD * ev512 * 1024.f;
    }
    return;
  }
  // ---- row pass (pure FMA) ----
  float S0 = 0.f, S1 = 0.f;
  #pragma unroll
  for (int q = 0; q < 8; ++q) { S0 += ee0[q] * evv[q]; S1 += ee1[q] * evv[q]; }
  if (lane == 0) { S0 += EDUST * ev512; S1 += EDUST * ev512; }
  #pragma unroll
  for (int off = 32; off; off >>= 1) {
    S0 += __shfl_xor(S0, off);
    S1 += __shfl_xor(S1, off);
  }
  const float eu0 = MU0 / S0, eu1 = MU0 / S1;
  if (lane == 0) { euBuf[r0] = eu0; euBuf[r1] = eu1; }
  float pacc[8];
  #pragma unroll
  for (int q = 0; q < 8; ++q) pacc[q] = ee0[q] * eu0 + ee1[q] * eu1;
  float pacc8 = EDUST * eu0 + EDUST * eu1;
  if (hasDust) {          // dust row: S_d = EDUST * sum(ev)
    float Sd = 0.f;
    #pragma unroll
    for (int q = 0; q < 8; ++q) Sd += evv[q];
    if (lane == 0) Sd += ev512;
    #pragma unroll
    for (int off = 32; off; off >>= 1) Sd += __shfl_xor(Sd, off);
    Sd *= EDUST;
    const float euD = MU1 / Sd;
    if (lane == 0) euBuf[512] = euD;
    #pragma unroll
    for (int q = 0; q < 8; ++q) pacc[q] += EDUST * euD;
    pacc8 += EDUST * euD;
  }
  *(float4*)&pcolw[widx][j0]   = make_float4(pacc[0], pacc[1], pacc[2], pacc[3]);
  *(float4*)&pcolw[widx][j0+4] = make_float4(pacc[4], pacc[5], pacc[6], pacc[7]);
  if (lane == 0) pcolw[widx][512] = pacc8;
  __syncthreads();
  float* pc = PcolOut + b*KP1;
  for (int j = t; j < KP1; j += 1024) {
    float s = 0.f;
    #pragma unroll
    for (int w = 0; w < 16; ++w) s += pcolw[w][j];
    pc[j] = s;
  }
}

extern "C" void kernel_launch(void* const* d_in, const int* in_sizes, int n_in,
                              void* d_out, int out_size, void* d_ws, size_t ws_size,
                              hipStream_t stream) {
  const float* img1 = (const float*)d_in[0];
  const float* img2 = (const float*)d_in[1];
  float* out = (float*)d_out;
  char* ws = (char*)d_ws;

  float* smooth = (float*)(ws + OFF_SMOOTH);
  unsigned long long* cand = (unsigned long long*)(ws + OFF_CAND);
  int*   kidx   = (int*)  (ws + OFF_KIDX);
  float* desc   = (float*)(ws + OFF_DESC);
  float* sbuf   = (float*)(ws + OFF_SBUF);
  float* E      = (float*)(ws + OFF_E);
  float* pcA    = (float*)(ws + OFF_PC);
  float* pcB    = (float*)(ws + OFF_PC) + SBK*KP1;
  float* euBuf  = (float*)(ws + OFF_EU);
  float* probsOut = out + 2*KK*2;

  detnms_kernel<<<dim3(20, 15, 2), dim3(16, 16), 0, stream>>>(img1, img2, smooth, cand);
  select2_kernel<<<2, 1024, 0, stream>>>(cand, out, kidx);
  desc_kernel<<<dim3(KK, 2), 256, 0, stream>>>(smooth, kidx, desc, sbuf);
  zbuild_kernel<<<dim3(16, 16), dim3(16, 16), 0, stream>>>(desc, sbuf, E);

  // L0: ev=1, row pass -> pcA
  sink_step_kernel<<<SBK, 1024, 0, stream>>>(E, pcB, pcA, euBuf, probsOut, 0);
  int ping = 0;  // latest slices in pcA
  for (int it = 1; it < 20; ++it) {
    float* pin  = ping ? pcB : pcA;
    float* pout = ping ? pcA : pcB;
    sink_step_kernel<<<SBK, 1024, 0, stream>>>(E, pin, pout, euBuf, probsOut, 1);
    ping ^= 1;
  }
  {
    float* pin = ping ? pcB : pcA;
    sink_step_kernel<<<SBK, 1024, 0, stream>>>(E, pin, pcA, euBuf, probsOut, 2);
  }
}